// Round 7
// baseline (505.541 us; speedup 1.0000x reference)
//
#include <hip/hip_runtime.h>
#include <stdint.h>

// Problem constants: B=2, S=2048, D=1024, H=16, HD=64, ROT_DIM=64(=HD)
#define S_LEN 2048
#define NHEAD 16
#define DMODEL 1024

typedef __attribute__((ext_vector_type(8))) short short8;
typedef __attribute__((ext_vector_type(8))) __bf16 bf16x8;
typedef __attribute__((ext_vector_type(4))) float f32x4;

__device__ __forceinline__ unsigned short f2b(float f) {
  unsigned int u = __float_as_uint(f);
  u += 0x7fffu + ((u >> 16) & 1u);   // round-to-nearest-even
  return (unsigned short)(u >> 16);
}
__device__ __forceinline__ float b2f(unsigned short h) {
  return __uint_as_float(((unsigned int)h) << 16);
}
__device__ __forceinline__ f32x4 mfma16(short8 a, short8 b, f32x4 c) {
  return __builtin_amdgcn_mfma_f32_16x16x32_bf16(
      __builtin_bit_cast(bf16x8, a), __builtin_bit_cast(bf16x8, b), c, 0, 0, 0);
}
__device__ __forceinline__ void gload16(const void* g, void* l) {
  __builtin_amdgcn_global_load_lds(
      (const __attribute__((address_space(1))) unsigned int*)g,
      (__attribute__((address_space(3))) unsigned int*)l, 16, 0, 0);
}

// ---------------- cast x (f32 -> bf16), vectorized ----------------
__global__ __launch_bounds__(256) void cast_f32_bf16(
    const float* __restrict__ in, unsigned short* __restrict__ out, long n) {
  long i = ((long)blockIdx.x * 256 + threadIdx.x) * 4;
  if (i >= n) return;
  float4 v = *(const float4*)(in + i);
  ushort4 o;
  o.x = f2b(v.x); o.y = f2b(v.y); o.z = f2b(v.z); o.w = f2b(v.w);
  *(ushort4*)(out + i) = o;
}

// ---------------- transpose + cast: W[K][N] f32 -> Wt[N][K] bf16 ----------------
__global__ __launch_bounds__(256) void transpose_cast(
    const float* __restrict__ W, unsigned short* __restrict__ Wt, int K, int N) {
  __shared__ float t[32][33];
  const int nt = blockIdx.x, kt = blockIdx.y;
  const int tx = threadIdx.x, ty = threadIdx.y; // (32, 8)
#pragma unroll
  for (int j = 0; j < 4; ++j)
    t[ty + j * 8][tx] = W[(long)(kt * 32 + ty + j * 8) * N + nt * 32 + tx];
  __syncthreads();
#pragma unroll
  for (int j = 0; j < 4; ++j)
    Wt[(long)(nt * 32 + ty + j * 8) * K + kt * 32 + tx] = f2b(t[tx][ty + j * 8]);
}

// ---------------- RoPE cos/sin table ----------------
__global__ __launch_bounds__(256) void make_tab(float2* __restrict__ tab) {
  int i = blockIdx.x * 256 + threadIdx.x;  // 2048*32
  if (i >= S_LEN * 32) return;
  int s = i >> 5, fi = i & 31;
  float inv = powf(10000.0f, -(float)(2 * fi) / 64.0f);
  float fr = (float)s * inv;
  tab[i] = make_float2(cosf(fr), sinf(fr));
}

// ---------------- GEMM: C[M][N] = A[M][K](bf16) * Bt[N][K](bf16)^T ----------------
template <int OUT_BF16>
__global__ __launch_bounds__(256) void gemm_bt(
    const unsigned short* __restrict__ A, const unsigned short* __restrict__ Bt,
    void* __restrict__ Cout, int M, int N, int K) {
  __shared__ __align__(16) unsigned short As[128 * 32];
  __shared__ __align__(16) unsigned short Bs[128 * 32];
  const int tid = threadIdx.x;
  const int wave = tid >> 6, lane = tid & 63;
  const int g = lane >> 4, r15 = lane & 15;
  const int wm = wave >> 1, wn = wave & 1;
  const long m0 = (long)blockIdx.x * 128, n0 = (long)blockIdx.y * 128;
  const int srow = tid >> 2, scol = (tid & 3) * 8;  // 16B per thread
  const unsigned short* Ag = A + (m0 + srow) * K + scol;
  const unsigned short* Bg = Bt + (n0 + srow) * K + scol;
  unsigned short* As0 = &As[srow * 32 + scol];
  unsigned short* As1 = &As[(srow + 64) * 32 + scol];
  unsigned short* Bs0 = &Bs[srow * 32 + scol];
  unsigned short* Bs1 = &Bs[(srow + 64) * 32 + scol];
  f32x4 acc[4][4] = {};
  for (int kt = 0; kt < K; kt += 32) {
    __syncthreads();
    gload16(Ag + kt, As0);
    gload16(Ag + (long)64 * K + kt, As1);
    gload16(Bg + kt, Bs0);
    gload16(Bg + (long)64 * K + kt, Bs1);
    __syncthreads();
    short8 a[4], b[4];
#pragma unroll
    for (int m = 0; m < 4; ++m)
      a[m] = *(const short8*)&As[(wm * 64 + m * 16 + r15) * 32 + g * 8];
#pragma unroll
    for (int n = 0; n < 4; ++n)
      b[n] = *(const short8*)&Bs[(wn * 64 + n * 16 + r15) * 32 + g * 8];
#pragma unroll
    for (int m = 0; m < 4; ++m)
#pragma unroll
      for (int n = 0; n < 4; ++n)
        acc[m][n] = mfma16(a[m], b[n], acc[m][n]);
  }
#pragma unroll
  for (int m = 0; m < 4; ++m)
#pragma unroll
    for (int n = 0; n < 4; ++n)
#pragma unroll
      for (int r = 0; r < 4; ++r) {
        long row = m0 + wm * 64 + m * 16 + g * 4 + r;
        long col = n0 + wn * 64 + n * 16 + r15;
        if (OUT_BF16)
          ((unsigned short*)Cout)[row * N + col] = f2b(acc[m][n][r]);
        else
          ((float*)Cout)[row * N + col] = acc[m][n][r];
      }
}

// ---------------- RoPE + scatter q,k ----------------
__global__ __launch_bounds__(256) void rope_scatter(
    const unsigned short* __restrict__ qkv, const float2* __restrict__ tab,
    unsigned short* __restrict__ Qb, unsigned short* __restrict__ Kb) {
  long p = (long)blockIdx.x * 256 + threadIdx.x;  // pair index, 4096*1024 total
  if (p >= (long)4096 * 1024) return;
  int row = (int)(p >> 10);
  int col = ((int)(p & 1023)) * 2;
  int seg = col >> 10;            // 0=q, 1=k
  int cc = col & 1023;
  int h = cc >> 6, d = cc & 63;
  int b = row >> 11, s = row & 2047;
  const unsigned short* src = qkv + (long)row * 3072 + col;
  float v0 = b2f(src[0]), v1 = b2f(src[1]);
  float2 f = tab[s * 32 + (d >> 1)];
  float o0 = v0 * f.x + v1 * f.y;
  float o1 = v1 * f.x - v0 * f.y;
  float scl = seg ? 1.0f : 0.125f;  // q pre-scaled by 1/sqrt(HD)
  unsigned short* dst = (seg ? Kb : Qb) + (((long)(b * NHEAD + h) * S_LEN + s) * 64 + d);
  dst[0] = f2b(o0 * scl);
  dst[1] = f2b(o1 * scl);
}

// ---------------- V transpose (PERMUTED): Vt[bh][d][col] ----------------
// Within each 64-kv block, column j holds kv = (j&3)*16 + (j>>2), matching the
// P-tile column layout produced by the attn kernel (lane c, subtile s -> col c*4+s).
__global__ __launch_bounds__(256) void v_transpose(
    const unsigned short* __restrict__ qkv, unsigned short* __restrict__ Vt) {
  __shared__ unsigned short t[64][33];
  const int st = blockIdx.x;   // 32 tiles of 64 kv
  const int dt = blockIdx.y;   // 2 tiles of 32 d
  const int bh = blockIdx.z;   // 32
  const int b = bh >> 4, h = bh & 15;
  const int tx = threadIdx.x, ty = threadIdx.y;  // (32, 8)
#pragma unroll
  for (int j = 0; j < 8; ++j)
    t[ty + j * 8][tx] =
        qkv[((long)b * S_LEN + st * 64 + ty + j * 8) * 3072 + 2048 + h * 64 + dt * 32 + tx];
  __syncthreads();
#pragma unroll
  for (int j = 0; j < 4; ++j) {
    const int d_local = ty + j * 8;          // 0..31
#pragma unroll
    for (int jj = 0; jj < 2; ++jj) {
      const int col = jj * 32 + tx;          // 0..63
      const int kv = (col & 3) * 16 + (col >> 2);
      Vt[((long)bh * 64 + dt * 32 + d_local) * S_LEN + st * 64 + col] = t[kv][d_local];
    }
  }
}

// ---------------- flash attention v3 ----------------
// UNPAIRED jobs: 4096 one-wave blocks, one 16-row q-tile each (was 2048 paired
// blocks -> only 8 waves/CU available; occupancy measured 11%, latency-bound).
// Longest-job-first dispatch per XCD; dynamic scheduling balances the triangle.
// K,V register-prefetched one tile ahead; P via swizzled wave-private LDS.
__device__ __forceinline__ void load_k(const unsigned short* __restrict__ Kp,
                                       int kpos, int c, int g, short8 kf[4][2]) {
#pragma unroll
  for (int s = 0; s < 4; ++s)
#pragma unroll
    for (int hh = 0; hh < 2; ++hh)
      kf[s][hh] = *(const short8*)(Kp + (long)(kpos + s * 16 + c) * 64 + hh * 32 + g * 8);
}
__device__ __forceinline__ void load_v(const unsigned short* __restrict__ Vp,
                                       int kpos, int c, int g, short8 vf[4][2]) {
#pragma unroll
  for (int dt = 0; dt < 4; ++dt)
#pragma unroll
    for (int hh = 0; hh < 2; ++hh)
      vf[dt][hh] = *(const short8*)(Vp + (long)(dt * 16 + c) * S_LEN + kpos + hh * 32 + g * 8);
}

template <bool MASKED, bool PREFETCH>
__device__ __forceinline__ void attn_tile(
    int kpos0, int qbase, int c, int g,
    const short8& q0, const short8& q1,
    short8 kf[4][2], short8 vf[4][2],
    f32x4 O[4], float mrow[4], float lrow[4],
    unsigned char* PwB,
    const unsigned short* __restrict__ Kp, const unsigned short* __restrict__ Vp) {
  f32x4 s[4];
#pragma unroll
  for (int sub = 0; sub < 4; ++sub) {
    f32x4 z = {};
    z = mfma16(q0, kf[sub][0], z);
    s[sub] = mfma16(q1, kf[sub][1], z);
  }
  if (PREFETCH) load_k(Kp, kpos0 + 64, c, g, kf);  // K(t+1): latency hidden under softmax+PV
  float sc[4];
#pragma unroll
  for (int r = 0; r < 4; ++r) {
    float a0 = s[0][r], a1 = s[1][r], a2 = s[2][r], a3 = s[3][r];
    if (MASKED) {
      const int q = qbase + g * 4 + r;
      a0 = (kpos0 + c <= q) ? a0 : -1e30f;
      a1 = (kpos0 + 16 + c <= q) ? a1 : -1e30f;
      a2 = (kpos0 + 32 + c <= q) ? a2 : -1e30f;
      a3 = (kpos0 + 48 + c <= q) ? a3 : -1e30f;
    }
    float mt = fmaxf(fmaxf(a0, a1), fmaxf(a2, a3));
    mt = fmaxf(mt, __shfl_xor(mt, 1));
    mt = fmaxf(mt, __shfl_xor(mt, 2));
    mt = fmaxf(mt, __shfl_xor(mt, 4));
    mt = fmaxf(mt, __shfl_xor(mt, 8));
    const float mnew = fmaxf(mrow[r], mt);
    sc[r] = __expf(mrow[r] - mnew);
    mrow[r] = mnew;
    a0 = __expf(a0 - mnew);
    a1 = __expf(a1 - mnew);
    a2 = __expf(a2 - mnew);
    a3 = __expf(a3 - mnew);
    float rs = (a0 + a1) + (a2 + a3);
    rs += __shfl_xor(rs, 1);
    rs += __shfl_xor(rs, 2);
    rs += __shfl_xor(rs, 4);
    rs += __shfl_xor(rs, 8);
    lrow[r] = lrow[r] * sc[r] + rs;
    // P row q=g*4+r, cols c*4+{0,1,2,3} (permuted kv order, matches Vt)
    unsigned int lo, hi;
    asm("v_cvt_pk_bf16_f32 %0, %1, %2" : "=v"(lo) : "v"(a0), "v"(a1));
    asm("v_cvt_pk_bf16_f32 %0, %1, %2" : "=v"(hi) : "v"(a2), "v"(a3));
    const int qr = g * 4 + r;
    *(uint2*)(PwB + qr * 128 + ((c * 8) ^ ((qr & 7) << 4))) = make_uint2(lo, hi);
  }
#pragma unroll
  for (int dt = 0; dt < 4; ++dt) {
    f32x4 o = O[dt];
    o[0] *= sc[0]; o[1] *= sc[1]; o[2] *= sc[2]; o[3] *= sc[3];
    O[dt] = o;
  }
  __builtin_amdgcn_wave_barrier();
  const int rb = c * 128, swz = (c & 7) << 4;
  const short8 pa0 = *(const short8*)(PwB + rb + ((g * 16) ^ swz));
  const short8 pa1 = *(const short8*)(PwB + rb + ((64 + g * 16) ^ swz));
#pragma unroll
  for (int dt = 0; dt < 4; ++dt) {
    O[dt] = mfma16(pa0, vf[dt][0], O[dt]);
    O[dt] = mfma16(pa1, vf[dt][1], O[dt]);
  }
  __builtin_amdgcn_wave_barrier();
  if (PREFETCH) load_v(Vp, kpos0 + 64, c, g, vf);  // V(t+1): hidden under next QK+softmax
}

__global__ __launch_bounds__(64, 4) void attn_v3(
    const unsigned short* __restrict__ Qb, const unsigned short* __restrict__ Kb,
    const unsigned short* __restrict__ Vt, unsigned short* __restrict__ yb) {
  __shared__ __align__(16) unsigned char PwB[2048];
  const int flat = (int)blockIdx.x + ((int)blockIdx.y << 7);  // 0..4095
  const int xcd = flat & 7;              // dispatch round-robins XCDs
  const int rest = flat >> 3;            // 0..511
  const int bh = xcd * 4 + (rest >> 7);  // 4 heads per XCD (2MB K+V < 4MB L2)
  const int p = 127 - (rest & 127);      // longest q-tile jobs dispatch first
  const int lane = (int)threadIdx.x & 63;
  const int g = lane >> 4, c = lane & 15;
  const int b = bh >> 4, h = bh & 15;
  const unsigned short* Kp = Kb + (long)bh * (S_LEN * 64);
  const unsigned short* Vp = Vt + (long)bh * (64 * S_LEN);
  short8 kf[4][2], vf[4][2];

  const int qbase = p << 4;
  const unsigned short* Qp = Qb + ((long)bh * S_LEN + qbase) * 64;
  const short8 q0 = *(const short8*)(Qp + c * 64 + g * 8);
  const short8 q1 = *(const short8*)(Qp + c * 64 + 32 + g * 8);
  f32x4 O[4] = {};
  float mrow[4] = {-1e30f, -1e30f, -1e30f, -1e30f};
  float lrow[4] = {0.f, 0.f, 0.f, 0.f};
  const int nfull = qbase >> 6;

  load_k(Kp, 0, c, g, kf);
  load_v(Vp, 0, c, g, vf);
  for (int t = 0; t < nfull; ++t)
    attn_tile<false, true>(t * 64, qbase, c, g, q0, q1, kf, vf, O, mrow, lrow, PwB, Kp, Vp);
  attn_tile<true, false>(nfull * 64, qbase, c, g, q0, q1, kf, vf, O, mrow, lrow, PwB, Kp, Vp);

  float inv[4];
#pragma unroll
  for (int r = 0; r < 4; ++r) inv[r] = 1.0f / lrow[r];
#pragma unroll
  for (int dt = 0; dt < 4; ++dt)
#pragma unroll
    for (int r = 0; r < 4; ++r) {
      long row = (long)b * S_LEN + qbase + g * 4 + r;
      yb[row * DMODEL + h * 64 + dt * 16 + c] = f2b(O[dt][r] * inv[r]);
    }
}

extern "C" void kernel_launch(void* const* d_in, const int* in_sizes, int n_in,
                              void* d_out, int out_size, void* d_ws, size_t ws_size,
                              hipStream_t stream) {
  const float* x = (const float*)d_in[0];       // [2,2048,1024]
  const float* Wa = (const float*)d_in[1];      // [1024,3072]
  const float* Wp = (const float*)d_in[2];      // [1024,1024]
  float* out = (float*)d_out;

  char* ws = (char*)d_ws;
  size_t off = 0;
  auto alloc = [&](size_t bytes) -> void* {
    off = (off + 255) & ~(size_t)255;
    void* p = ws + off;
    off += bytes;
    return p;
  };
  unsigned short* xb   = (unsigned short*)alloc((size_t)4096 * 1024 * 2);
  unsigned short* WaT  = (unsigned short*)alloc((size_t)3072 * 1024 * 2);
  unsigned short* WpT  = (unsigned short*)alloc((size_t)1024 * 1024 * 2);
  unsigned short* qkvb = (unsigned short*)alloc((size_t)4096 * 3072 * 2);
  float2* tab          = (float2*)alloc((size_t)2048 * 32 * sizeof(float2));
  unsigned short* Qb   = (unsigned short*)alloc((size_t)32 * 2048 * 64 * 2);
  unsigned short* Kb   = (unsigned short*)alloc((size_t)32 * 2048 * 64 * 2);
  unsigned short* Vt   = (unsigned short*)alloc((size_t)32 * 2048 * 64 * 2);
  unsigned short* yb   = xb;  // alias: xb dead after gemm1

  dim3 tB(32, 8);
  cast_f32_bf16<<<4096, 256, 0, stream>>>(x, xb, (long)4096 * 1024);
  transpose_cast<<<dim3(96, 32), tB, 0, stream>>>(Wa, WaT, 1024, 3072);
  transpose_cast<<<dim3(32, 32), tB, 0, stream>>>(Wp, WpT, 1024, 1024);
  make_tab<<<256, 256, 0, stream>>>(tab);
  gemm_bt<1><<<dim3(32, 24), 256, 0, stream>>>(xb, WaT, (void*)qkvb, 4096, 3072, 1024);
  rope_scatter<<<16384, 256, 0, stream>>>(qkvb, tab, Qb, Kb);
  v_transpose<<<dim3(32, 2, 32), tB, 0, stream>>>(qkvb, Vt);
  attn_v3<<<dim3(128, 32), 64, 0, stream>>>(Qb, Kb, Vt, yb);
  gemm_bt<0><<<dim3(32, 8), 256, 0, stream>>>(yb, WpT, (void*)out, 4096, 1024, 1024);
}

// Round 8
// 316.959 us; speedup vs baseline: 1.5950x; 1.5950x over previous
//
#include <hip/hip_runtime.h>
#include <stdint.h>

// Problem constants: B=2, S=2048, D=1024, H=16, HD=64, ROT_DIM=64(=HD)
#define S_LEN 2048
#define NHEAD 16
#define DMODEL 1024

typedef __attribute__((ext_vector_type(8))) short short8;
typedef __attribute__((ext_vector_type(8))) __bf16 bf16x8;
typedef __attribute__((ext_vector_type(4))) float f32x4;

__device__ __forceinline__ unsigned short f2b(float f) {
  unsigned int u = __float_as_uint(f);
  u += 0x7fffu + ((u >> 16) & 1u);   // round-to-nearest-even
  return (unsigned short)(u >> 16);
}
__device__ __forceinline__ float b2f(unsigned short h) {
  return __uint_as_float(((unsigned int)h) << 16);
}
__device__ __forceinline__ f32x4 mfma16(short8 a, short8 b, f32x4 c) {
  return __builtin_amdgcn_mfma_f32_16x16x32_bf16(
      __builtin_bit_cast(bf16x8, a), __builtin_bit_cast(bf16x8, b), c, 0, 0, 0);
}
__device__ __forceinline__ void gload16(const void* g, void* l) {
  __builtin_amdgcn_global_load_lds(
      (const __attribute__((address_space(1))) unsigned int*)g,
      (__attribute__((address_space(3))) unsigned int*)l, 16, 0, 0);
}

// ---------------- cast x (f32 -> bf16), vectorized ----------------
__global__ __launch_bounds__(256) void cast_f32_bf16(
    const float* __restrict__ in, unsigned short* __restrict__ out, long n) {
  long i = ((long)blockIdx.x * 256 + threadIdx.x) * 4;
  if (i >= n) return;
  float4 v = *(const float4*)(in + i);
  ushort4 o;
  o.x = f2b(v.x); o.y = f2b(v.y); o.z = f2b(v.z); o.w = f2b(v.w);
  *(ushort4*)(out + i) = o;
}

// ---------------- transpose + cast: W[K][N] f32 -> Wt[N][K] bf16 ----------------
__global__ __launch_bounds__(256) void transpose_cast(
    const float* __restrict__ W, unsigned short* __restrict__ Wt, int K, int N) {
  __shared__ float t[32][33];
  const int nt = blockIdx.x, kt = blockIdx.y;
  const int tx = threadIdx.x, ty = threadIdx.y; // (32, 8)
#pragma unroll
  for (int j = 0; j < 4; ++j)
    t[ty + j * 8][tx] = W[(long)(kt * 32 + ty + j * 8) * N + nt * 32 + tx];
  __syncthreads();
#pragma unroll
  for (int j = 0; j < 4; ++j)
    Wt[(long)(nt * 32 + ty + j * 8) * K + kt * 32 + tx] = f2b(t[tx][ty + j * 8]);
}

// ---------------- RoPE cos/sin table ----------------
__global__ __launch_bounds__(256) void make_tab(float2* __restrict__ tab) {
  int i = blockIdx.x * 256 + threadIdx.x;  // 2048*32
  if (i >= S_LEN * 32) return;
  int s = i >> 5, fi = i & 31;
  float inv = powf(10000.0f, -(float)(2 * fi) / 64.0f);
  float fr = (float)s * inv;
  tab[i] = make_float2(cosf(fr), sinf(fr));
}

// ---------------- GEMM: C[M][N] = A[M][K](bf16) * Bt[N][K](bf16)^T ----------------
template <int OUT_BF16>
__global__ __launch_bounds__(256) void gemm_bt(
    const unsigned short* __restrict__ A, const unsigned short* __restrict__ Bt,
    void* __restrict__ Cout, int M, int N, int K) {
  __shared__ __align__(16) unsigned short As[128 * 32];
  __shared__ __align__(16) unsigned short Bs[128 * 32];
  const int tid = threadIdx.x;
  const int wave = tid >> 6, lane = tid & 63;
  const int g = lane >> 4, r15 = lane & 15;
  const int wm = wave >> 1, wn = wave & 1;
  const long m0 = (long)blockIdx.x * 128, n0 = (long)blockIdx.y * 128;
  const int srow = tid >> 2, scol = (tid & 3) * 8;  // 16B per thread
  const unsigned short* Ag = A + (m0 + srow) * K + scol;
  const unsigned short* Bg = Bt + (n0 + srow) * K + scol;
  unsigned short* As0 = &As[srow * 32 + scol];
  unsigned short* As1 = &As[(srow + 64) * 32 + scol];
  unsigned short* Bs0 = &Bs[srow * 32 + scol];
  unsigned short* Bs1 = &Bs[(srow + 64) * 32 + scol];
  f32x4 acc[4][4] = {};
  for (int kt = 0; kt < K; kt += 32) {
    __syncthreads();
    gload16(Ag + kt, As0);
    gload16(Ag + (long)64 * K + kt, As1);
    gload16(Bg + kt, Bs0);
    gload16(Bg + (long)64 * K + kt, Bs1);
    __syncthreads();
    short8 a[4], b[4];
#pragma unroll
    for (int m = 0; m < 4; ++m)
      a[m] = *(const short8*)&As[(wm * 64 + m * 16 + r15) * 32 + g * 8];
#pragma unroll
    for (int n = 0; n < 4; ++n)
      b[n] = *(const short8*)&Bs[(wn * 64 + n * 16 + r15) * 32 + g * 8];
#pragma unroll
    for (int m = 0; m < 4; ++m)
#pragma unroll
      for (int n = 0; n < 4; ++n)
        acc[m][n] = mfma16(a[m], b[n], acc[m][n]);
  }
#pragma unroll
  for (int m = 0; m < 4; ++m)
#pragma unroll
    for (int n = 0; n < 4; ++n)
#pragma unroll
      for (int r = 0; r < 4; ++r) {
        long row = m0 + wm * 64 + m * 16 + g * 4 + r;
        long col = n0 + wn * 64 + n * 16 + r15;
        if (OUT_BF16)
          ((unsigned short*)Cout)[row * N + col] = f2b(acc[m][n][r]);
        else
          ((float*)Cout)[row * N + col] = acc[m][n][r];
      }
}

// ---------------- RoPE + scatter q,k ----------------
__global__ __launch_bounds__(256) void rope_scatter(
    const unsigned short* __restrict__ qkv, const float2* __restrict__ tab,
    unsigned short* __restrict__ Qb, unsigned short* __restrict__ Kb) {
  long p = (long)blockIdx.x * 256 + threadIdx.x;  // pair index, 4096*1024 total
  if (p >= (long)4096 * 1024) return;
  int row = (int)(p >> 10);
  int col = ((int)(p & 1023)) * 2;
  int seg = col >> 10;            // 0=q, 1=k
  int cc = col & 1023;
  int h = cc >> 6, d = cc & 63;
  int b = row >> 11, s = row & 2047;
  const unsigned short* src = qkv + (long)row * 3072 + col;
  float v0 = b2f(src[0]), v1 = b2f(src[1]);
  float2 f = tab[s * 32 + (d >> 1)];
  float o0 = v0 * f.x + v1 * f.y;
  float o1 = v1 * f.x - v0 * f.y;
  float scl = seg ? 1.0f : 0.125f;  // q pre-scaled by 1/sqrt(HD)
  unsigned short* dst = (seg ? Kb : Qb) + (((long)(b * NHEAD + h) * S_LEN + s) * 64 + d);
  dst[0] = f2b(o0 * scl);
  dst[1] = f2b(o1 * scl);
}

// ---------------- V transpose (PERMUTED): Vt[bh][d][col] ----------------
// Within each 64-kv block, column j holds kv = (j&3)*16 + (j>>2), matching the
// P-tile column layout produced by the attn kernel (lane c, subtile s -> col c*4+s).
__global__ __launch_bounds__(256) void v_transpose(
    const unsigned short* __restrict__ qkv, unsigned short* __restrict__ Vt) {
  __shared__ unsigned short t[64][33];
  const int st = blockIdx.x;   // 32 tiles of 64 kv
  const int dt = blockIdx.y;   // 2 tiles of 32 d
  const int bh = blockIdx.z;   // 32
  const int b = bh >> 4, h = bh & 15;
  const int tx = threadIdx.x, ty = threadIdx.y;  // (32, 8)
#pragma unroll
  for (int j = 0; j < 8; ++j)
    t[ty + j * 8][tx] =
        qkv[((long)b * S_LEN + st * 64 + ty + j * 8) * 3072 + 2048 + h * 64 + dt * 32 + tx];
  __syncthreads();
#pragma unroll
  for (int j = 0; j < 4; ++j) {
    const int d_local = ty + j * 8;          // 0..31
#pragma unroll
    for (int jj = 0; jj < 2; ++jj) {
      const int col = jj * 32 + tx;          // 0..63
      const int kv = (col & 3) * 16 + (col >> 2);
      Vt[((long)bh * 64 + dt * 32 + d_local) * S_LEN + st * 64 + col] = t[kv][d_local];
    }
  }
}

// ---------------- flash attention v3b ----------------
// UNPAIRED jobs (4096 one-wave blocks; 16 waves/CU supply) with PLAIN
// __launch_bounds__(64): round-7's (64,4) capped VGPR at 64 -> 903 MB scratch
// spill (WRITE_SIZE counter), 337us. At ~132 VGPR: 3 waves/SIMD, no spill.
__device__ __forceinline__ void load_k(const unsigned short* __restrict__ Kp,
                                       int kpos, int c, int g, short8 kf[4][2]) {
#pragma unroll
  for (int s = 0; s < 4; ++s)
#pragma unroll
    for (int hh = 0; hh < 2; ++hh)
      kf[s][hh] = *(const short8*)(Kp + (long)(kpos + s * 16 + c) * 64 + hh * 32 + g * 8);
}
__device__ __forceinline__ void load_v(const unsigned short* __restrict__ Vp,
                                       int kpos, int c, int g, short8 vf[4][2]) {
#pragma unroll
  for (int dt = 0; dt < 4; ++dt)
#pragma unroll
    for (int hh = 0; hh < 2; ++hh)
      vf[dt][hh] = *(const short8*)(Vp + (long)(dt * 16 + c) * S_LEN + kpos + hh * 32 + g * 8);
}

template <bool MASKED, bool PREFETCH>
__device__ __forceinline__ void attn_tile(
    int kpos0, int qbase, int c, int g,
    const short8& q0, const short8& q1,
    short8 kf[4][2], short8 vf[4][2],
    f32x4 O[4], float mrow[4], float lrow[4],
    unsigned char* PwB,
    const unsigned short* __restrict__ Kp, const unsigned short* __restrict__ Vp) {
  f32x4 s[4];
#pragma unroll
  for (int sub = 0; sub < 4; ++sub) {
    f32x4 z = {};
    z = mfma16(q0, kf[sub][0], z);
    s[sub] = mfma16(q1, kf[sub][1], z);
  }
  if (PREFETCH) load_k(Kp, kpos0 + 64, c, g, kf);  // K(t+1): latency hidden under softmax+PV
  float sc[4];
#pragma unroll
  for (int r = 0; r < 4; ++r) {
    float a0 = s[0][r], a1 = s[1][r], a2 = s[2][r], a3 = s[3][r];
    if (MASKED) {
      const int q = qbase + g * 4 + r;
      a0 = (kpos0 + c <= q) ? a0 : -1e30f;
      a1 = (kpos0 + 16 + c <= q) ? a1 : -1e30f;
      a2 = (kpos0 + 32 + c <= q) ? a2 : -1e30f;
      a3 = (kpos0 + 48 + c <= q) ? a3 : -1e30f;
    }
    float mt = fmaxf(fmaxf(a0, a1), fmaxf(a2, a3));
    mt = fmaxf(mt, __shfl_xor(mt, 1));
    mt = fmaxf(mt, __shfl_xor(mt, 2));
    mt = fmaxf(mt, __shfl_xor(mt, 4));
    mt = fmaxf(mt, __shfl_xor(mt, 8));
    const float mnew = fmaxf(mrow[r], mt);
    sc[r] = __expf(mrow[r] - mnew);
    mrow[r] = mnew;
    a0 = __expf(a0 - mnew);
    a1 = __expf(a1 - mnew);
    a2 = __expf(a2 - mnew);
    a3 = __expf(a3 - mnew);
    float rs = (a0 + a1) + (a2 + a3);
    rs += __shfl_xor(rs, 1);
    rs += __shfl_xor(rs, 2);
    rs += __shfl_xor(rs, 4);
    rs += __shfl_xor(rs, 8);
    lrow[r] = lrow[r] * sc[r] + rs;
    // P row q=g*4+r, cols c*4+{0,1,2,3} (permuted kv order, matches Vt)
    unsigned int lo, hi;
    asm("v_cvt_pk_bf16_f32 %0, %1, %2" : "=v"(lo) : "v"(a0), "v"(a1));
    asm("v_cvt_pk_bf16_f32 %0, %1, %2" : "=v"(hi) : "v"(a2), "v"(a3));
    const int qr = g * 4 + r;
    *(uint2*)(PwB + qr * 128 + ((c * 8) ^ ((qr & 7) << 4))) = make_uint2(lo, hi);
  }
#pragma unroll
  for (int dt = 0; dt < 4; ++dt) {
    f32x4 o = O[dt];
    o[0] *= sc[0]; o[1] *= sc[1]; o[2] *= sc[2]; o[3] *= sc[3];
    O[dt] = o;
  }
  __builtin_amdgcn_wave_barrier();
  const int rb = c * 128, swz = (c & 7) << 4;
  const short8 pa0 = *(const short8*)(PwB + rb + ((g * 16) ^ swz));
  const short8 pa1 = *(const short8*)(PwB + rb + ((64 + g * 16) ^ swz));
#pragma unroll
  for (int dt = 0; dt < 4; ++dt) {
    O[dt] = mfma16(pa0, vf[dt][0], O[dt]);
    O[dt] = mfma16(pa1, vf[dt][1], O[dt]);
  }
  __builtin_amdgcn_wave_barrier();
  if (PREFETCH) load_v(Vp, kpos0 + 64, c, g, vf);  // V(t+1): hidden under next QK+softmax
}

__global__ __launch_bounds__(64) void attn_v3(
    const unsigned short* __restrict__ Qb, const unsigned short* __restrict__ Kb,
    const unsigned short* __restrict__ Vt, unsigned short* __restrict__ yb) {
  __shared__ __align__(16) unsigned char PwB[2048];
  const int flat = (int)blockIdx.x + ((int)blockIdx.y << 7);  // 0..4095
  const int xcd = flat & 7;              // dispatch round-robins XCDs
  const int rest = flat >> 3;            // 0..511
  const int bh = xcd * 4 + (rest >> 7);  // 4 heads per XCD (2MB K+V < 4MB L2)
  const int p = 127 - (rest & 127);      // longest q-tile jobs dispatch first
  const int lane = (int)threadIdx.x & 63;
  const int g = lane >> 4, c = lane & 15;
  const int b = bh >> 4, h = bh & 15;
  const unsigned short* Kp = Kb + (long)bh * (S_LEN * 64);
  const unsigned short* Vp = Vt + (long)bh * (64 * S_LEN);
  short8 kf[4][2], vf[4][2];

  const int qbase = p << 4;
  const unsigned short* Qp = Qb + ((long)bh * S_LEN + qbase) * 64;
  const short8 q0 = *(const short8*)(Qp + c * 64 + g * 8);
  const short8 q1 = *(const short8*)(Qp + c * 64 + 32 + g * 8);
  f32x4 O[4] = {};
  float mrow[4] = {-1e30f, -1e30f, -1e30f, -1e30f};
  float lrow[4] = {0.f, 0.f, 0.f, 0.f};
  const int nfull = qbase >> 6;

  load_k(Kp, 0, c, g, kf);
  load_v(Vp, 0, c, g, vf);
  for (int t = 0; t < nfull; ++t)
    attn_tile<false, true>(t * 64, qbase, c, g, q0, q1, kf, vf, O, mrow, lrow, PwB, Kp, Vp);
  attn_tile<true, false>(nfull * 64, qbase, c, g, q0, q1, kf, vf, O, mrow, lrow, PwB, Kp, Vp);

  float inv[4];
#pragma unroll
  for (int r = 0; r < 4; ++r) inv[r] = 1.0f / lrow[r];
#pragma unroll
  for (int dt = 0; dt < 4; ++dt)
#pragma unroll
    for (int r = 0; r < 4; ++r) {
      long row = (long)b * S_LEN + qbase + g * 4 + r;
      yb[row * DMODEL + h * 64 + dt * 16 + c] = f2b(O[dt][r] * inv[r]);
    }
}

extern "C" void kernel_launch(void* const* d_in, const int* in_sizes, int n_in,
                              void* d_out, int out_size, void* d_ws, size_t ws_size,
                              hipStream_t stream) {
  const float* x = (const float*)d_in[0];       // [2,2048,1024]
  const float* Wa = (const float*)d_in[1];      // [1024,3072]
  const float* Wp = (const float*)d_in[2];      // [1024,1024]
  float* out = (float*)d_out;

  char* ws = (char*)d_ws;
  size_t off = 0;
  auto alloc = [&](size_t bytes) -> void* {
    off = (off + 255) & ~(size_t)255;
    void* p = ws + off;
    off += bytes;
    return p;
  };
  unsigned short* xb   = (unsigned short*)alloc((size_t)4096 * 1024 * 2);
  unsigned short* WaT  = (unsigned short*)alloc((size_t)3072 * 1024 * 2);
  unsigned short* WpT  = (unsigned short*)alloc((size_t)1024 * 1024 * 2);
  unsigned short* qkvb = (unsigned short*)alloc((size_t)4096 * 3072 * 2);
  float2* tab          = (float2*)alloc((size_t)2048 * 32 * sizeof(float2));
  unsigned short* Qb   = (unsigned short*)alloc((size_t)32 * 2048 * 64 * 2);
  unsigned short* Kb   = (unsigned short*)alloc((size_t)32 * 2048 * 64 * 2);
  unsigned short* Vt   = (unsigned short*)alloc((size_t)32 * 2048 * 64 * 2);
  unsigned short* yb   = xb;  // alias: xb dead after gemm1

  dim3 tB(32, 8);
  cast_f32_bf16<<<4096, 256, 0, stream>>>(x, xb, (long)4096 * 1024);
  transpose_cast<<<dim3(96, 32), tB, 0, stream>>>(Wa, WaT, 1024, 3072);
  transpose_cast<<<dim3(32, 32), tB, 0, stream>>>(Wp, WpT, 1024, 1024);
  make_tab<<<256, 256, 0, stream>>>(tab);
  gemm_bt<1><<<dim3(32, 24), 256, 0, stream>>>(xb, WaT, (void*)qkvb, 4096, 3072, 1024);
  rope_scatter<<<16384, 256, 0, stream>>>(qkvb, tab, Qb, Kb);
  v_transpose<<<dim3(32, 2, 32), tB, 0, stream>>>(qkvb, Vt);
  attn_v3<<<dim3(128, 32), 64, 0, stream>>>(Qb, Kb, Vt, yb);
  gemm_bt<0><<<dim3(32, 8), 256, 0, stream>>>(yb, WpT, (void*)out, 4096, 1024, 1024);
}

// Round 10
// 277.241 us; speedup vs baseline: 1.8235x; 1.1433x over previous
//
#include <hip/hip_runtime.h>
#include <stdint.h>

// Problem constants: B=2, S=2048, D=1024, H=16, HD=64, ROT_DIM=64(=HD)
#define S_LEN 2048
#define NHEAD 16
#define DMODEL 1024

typedef __attribute__((ext_vector_type(8))) short short8;
typedef __attribute__((ext_vector_type(8))) __bf16 bf16x8;
typedef __attribute__((ext_vector_type(4))) float f32x4;
typedef __attribute__((ext_vector_type(16))) float f32x16;

__device__ __forceinline__ unsigned short f2b(float f) {
  unsigned int u = __float_as_uint(f);
  u += 0x7fffu + ((u >> 16) & 1u);   // round-to-nearest-even
  return (unsigned short)(u >> 16);
}
__device__ __forceinline__ float b2f(unsigned short h) {
  return __uint_as_float(((unsigned int)h) << 16);
}
__device__ __forceinline__ f32x4 mfma16(short8 a, short8 b, f32x4 c) {
  return __builtin_amdgcn_mfma_f32_16x16x32_bf16(
      __builtin_bit_cast(bf16x8, a), __builtin_bit_cast(bf16x8, b), c, 0, 0, 0);
}
__device__ __forceinline__ f32x16 mfma32(short8 a, short8 b, f32x16 c) {
  return __builtin_amdgcn_mfma_f32_32x32x16_bf16(
      __builtin_bit_cast(bf16x8, a), __builtin_bit_cast(bf16x8, b), c, 0, 0, 0);
}
__device__ __forceinline__ unsigned int cvtpk(float lo, float hi) {
  unsigned int r;
  asm("v_cvt_pk_bf16_f32 %0, %1, %2" : "=v"(r) : "v"(lo), "v"(hi));
  return r;
}
__device__ __forceinline__ void gload16(const void* g, void* l) {
  __builtin_amdgcn_global_load_lds(
      (const __attribute__((address_space(1))) unsigned int*)g,
      (__attribute__((address_space(3))) unsigned int*)l, 16, 0, 0);
}

// ---------------- cast x (f32 -> bf16), vectorized ----------------
__global__ __launch_bounds__(256) void cast_f32_bf16(
    const float* __restrict__ in, unsigned short* __restrict__ out, long n) {
  long i = ((long)blockIdx.x * 256 + threadIdx.x) * 4;
  if (i >= n) return;
  float4 v = *(const float4*)(in + i);
  ushort4 o;
  o.x = f2b(v.x); o.y = f2b(v.y); o.z = f2b(v.z); o.w = f2b(v.w);
  *(ushort4*)(out + i) = o;
}

// ---------------- transpose + cast: W[K][N] f32 -> Wt[N][K] bf16 ----------------
__global__ __launch_bounds__(256) void transpose_cast(
    const float* __restrict__ W, unsigned short* __restrict__ Wt, int K, int N) {
  __shared__ float t[32][33];
  const int nt = blockIdx.x, kt = blockIdx.y;
  const int tx = threadIdx.x, ty = threadIdx.y; // (32, 8)
#pragma unroll
  for (int j = 0; j < 4; ++j)
    t[ty + j * 8][tx] = W[(long)(kt * 32 + ty + j * 8) * N + nt * 32 + tx];
  __syncthreads();
#pragma unroll
  for (int j = 0; j < 4; ++j)
    Wt[(long)(nt * 32 + ty + j * 8) * K + kt * 32 + tx] = f2b(t[tx][ty + j * 8]);
}

// ---------------- RoPE cos/sin table ----------------
__global__ __launch_bounds__(256) void make_tab(float2* __restrict__ tab) {
  int i = blockIdx.x * 256 + threadIdx.x;  // 2048*32
  if (i >= S_LEN * 32) return;
  int s = i >> 5, fi = i & 31;
  float inv = powf(10000.0f, -(float)(2 * fi) / 64.0f);
  float fr = (float)s * inv;
  tab[i] = make_float2(cosf(fr), sinf(fr));
}

// ---------------- GEMM: C[M][N] = A[M][K](bf16) * Bt[N][K](bf16)^T ----------------
template <int OUT_BF16>
__global__ __launch_bounds__(256) void gemm_bt(
    const unsigned short* __restrict__ A, const unsigned short* __restrict__ Bt,
    void* __restrict__ Cout, int M, int N, int K) {
  __shared__ __align__(16) unsigned short As[128 * 32];
  __shared__ __align__(16) unsigned short Bs[128 * 32];
  const int tid = threadIdx.x;
  const int wave = tid >> 6, lane = tid & 63;
  const int g = lane >> 4, r15 = lane & 15;
  const int wm = wave >> 1, wn = wave & 1;
  const long m0 = (long)blockIdx.x * 128, n0 = (long)blockIdx.y * 128;
  const int srow = tid >> 2, scol = (tid & 3) * 8;  // 16B per thread
  const unsigned short* Ag = A + (m0 + srow) * K + scol;
  const unsigned short* Bg = Bt + (n0 + srow) * K + scol;
  unsigned short* As0 = &As[srow * 32 + scol];
  unsigned short* As1 = &As[(srow + 64) * 32 + scol];
  unsigned short* Bs0 = &Bs[srow * 32 + scol];
  unsigned short* Bs1 = &Bs[(srow + 64) * 32 + scol];
  f32x4 acc[4][4] = {};
  for (int kt = 0; kt < K; kt += 32) {
    __syncthreads();
    gload16(Ag + kt, As0);
    gload16(Ag + (long)64 * K + kt, As1);
    gload16(Bg + kt, Bs0);
    gload16(Bg + (long)64 * K + kt, Bs1);
    __syncthreads();
    short8 a[4], b[4];
#pragma unroll
    for (int m = 0; m < 4; ++m)
      a[m] = *(const short8*)&As[(wm * 64 + m * 16 + r15) * 32 + g * 8];
#pragma unroll
    for (int n = 0; n < 4; ++n)
      b[n] = *(const short8*)&Bs[(wn * 64 + n * 16 + r15) * 32 + g * 8];
#pragma unroll
    for (int m = 0; m < 4; ++m)
#pragma unroll
      for (int n = 0; n < 4; ++n)
        acc[m][n] = mfma16(a[m], b[n], acc[m][n]);
  }
#pragma unroll
  for (int m = 0; m < 4; ++m)
#pragma unroll
    for (int n = 0; n < 4; ++n)
#pragma unroll
      for (int r = 0; r < 4; ++r) {
        long row = m0 + wm * 64 + m * 16 + g * 4 + r;
        long col = n0 + wn * 64 + n * 16 + r15;
        if (OUT_BF16)
          ((unsigned short*)Cout)[row * N + col] = f2b(acc[m][n][r]);
        else
          ((float*)Cout)[row * N + col] = acc[m][n][r];
      }
}

// ---------------- RoPE + scatter q,k ----------------
__global__ __launch_bounds__(256) void rope_scatter(
    const unsigned short* __restrict__ qkv, const float2* __restrict__ tab,
    unsigned short* __restrict__ Qb, unsigned short* __restrict__ Kb) {
  long p = (long)blockIdx.x * 256 + threadIdx.x;  // pair index, 4096*1024 total
  if (p >= (long)4096 * 1024) return;
  int row = (int)(p >> 10);
  int col = ((int)(p & 1023)) * 2;
  int seg = col >> 10;            // 0=q, 1=k
  int cc = col & 1023;
  int h = cc >> 6, d = cc & 63;
  int b = row >> 11, s = row & 2047;
  const unsigned short* src = qkv + (long)row * 3072 + col;
  float v0 = b2f(src[0]), v1 = b2f(src[1]);
  float2 f = tab[s * 32 + (d >> 1)];
  float o0 = v0 * f.x + v1 * f.y;
  float o1 = v1 * f.x - v0 * f.y;
  float scl = seg ? 1.0f : 0.125f;  // q pre-scaled by 1/sqrt(HD)
  unsigned short* dst = (seg ? Kb : Qb) + (((long)(b * NHEAD + h) * S_LEN + s) * 64 + d);
  dst[0] = f2b(o0 * scl);
  dst[1] = f2b(o1 * scl);
}

// ---------------- V transpose (plain): Vt[bh][d][kv] ----------------
__global__ __launch_bounds__(256) void v_transpose(
    const unsigned short* __restrict__ qkv, unsigned short* __restrict__ Vt) {
  __shared__ unsigned short t[64][33];
  const int st = blockIdx.x;   // 32 tiles of 64 kv
  const int dt = blockIdx.y;   // 2 tiles of 32 d
  const int bh = blockIdx.z;   // 32
  const int b = bh >> 4, h = bh & 15;
  const int tx = threadIdx.x, ty = threadIdx.y;  // (32, 8)
#pragma unroll
  for (int j = 0; j < 8; ++j)
    t[ty + j * 8][tx] =
        qkv[((long)b * S_LEN + st * 64 + ty + j * 8) * 3072 + 2048 + h * 64 + dt * 32 + tx];
  __syncthreads();
#pragma unroll
  for (int j = 0; j < 4; ++j) {
    const int d_local = ty + j * 8;          // 0..31
#pragma unroll
    for (int jj = 0; jj < 2; ++jj) {
      const int col = jj * 32 + tx;          // 0..63
      Vt[((long)bh * 64 + dt * 32 + d_local) * S_LEN + st * 64 + col] = t[col][d_local];
    }
  }
}

// ---------------- flash attention v4: swapped QK^T, in-register softmax ----------------
// 1 wave per 32 q-rows (2048 one-wave blocks). S^T = mfma32(K, Q): lane owns one
// q-column; kv = (reg&3)+8*(reg>>2)+4*(lane>>5). Softmax = in-reg tree + ONE
// shfl_xor(32) (vs 8 chained bpermutes in v2). P assembled in-register via
// cvt_pk + 4 independent shfl_xor(32) per kv16-chunk; PV = mfma32(V^T, P) -> O^T.
// Zero LDS, no barriers. K/V register-prefetched one tile ahead (v2 pattern).
__device__ __forceinline__ void load_k32(const unsigned short* __restrict__ Kp,
                                         int kv0, int q31, int hi, short8 kf[2][4]) {
#pragma unroll
  for (int sub = 0; sub < 2; ++sub)
#pragma unroll
    for (int dc = 0; dc < 4; ++dc)
      kf[sub][dc] = *(const short8*)(Kp + (long)(kv0 + sub * 32 + q31) * 64 + dc * 16 + hi * 8);
}
__device__ __forceinline__ void load_v32(const unsigned short* __restrict__ Vp,
                                         int kv0, int q31, int hi, short8 vf[2][4]) {
#pragma unroll
  for (int dv = 0; dv < 2; ++dv)
#pragma unroll
    for (int c = 0; c < 4; ++c)
      vf[dv][c] = *(const short8*)(Vp + (long)(dv * 32 + q31) * S_LEN + kv0 + c * 16 + hi * 8);
}

template <bool MASKED, bool PREFETCH>
__device__ __forceinline__ void attn_tile32(
    int kv0, int qbase, int q31, int hi,
    const short8 qf[4], short8 kf[2][4], short8 vf[2][4],
    f32x16& o0, f32x16& o1, float& m, float& l,
    const unsigned short* __restrict__ Kp, const unsigned short* __restrict__ Vp) {
  f32x16 s0 = {}, s1 = {};
#pragma unroll
  for (int dc = 0; dc < 4; ++dc) s0 = mfma32(kf[0][dc], qf[dc], s0);
#pragma unroll
  for (int dc = 0; dc < 4; ++dc) s1 = mfma32(kf[1][dc], qf[dc], s1);
  if (PREFETCH) load_k32(Kp, kv0 + 64, q31, hi, kf);  // hidden under softmax+PV
  if (MASKED) {
    const int q = qbase + q31;
#pragma unroll
    for (int i = 0; i < 16; ++i) {
      const int rel = (i & 3) + 8 * (i >> 2) + 4 * hi;
      s0[i] = (kv0 + rel <= q) ? s0[i] : -1e30f;
      s1[i] = (kv0 + 32 + rel <= q) ? s1[i] : -1e30f;
    }
  }
  // row max over 64 kv: in-register tree over 32 + one cross-half shfl
  float t8[8];
#pragma unroll
  for (int i = 0; i < 8; ++i)
    t8[i] = fmaxf(fmaxf(s0[2 * i], s0[2 * i + 1]), fmaxf(s1[2 * i], s1[2 * i + 1]));
  float mt = fmaxf(fmaxf(fmaxf(t8[0], t8[1]), fmaxf(t8[2], t8[3])),
                   fmaxf(fmaxf(t8[4], t8[5]), fmaxf(t8[6], t8[7])));
  mt = fmaxf(mt, __shfl_xor(mt, 32));
  const float mnew = fmaxf(m, mt);
  const float scl = __expf(m - mnew);
  m = mnew;
#pragma unroll
  for (int i = 0; i < 16; ++i) {
    s0[i] = __expf(s0[i] - mnew);
    s1[i] = __expf(s1[i] - mnew);
  }
  float a8[8];
#pragma unroll
  for (int i = 0; i < 8; ++i)
    a8[i] = (s0[2 * i] + s0[2 * i + 1]) + (s1[2 * i] + s1[2 * i + 1]);
  float rs = ((a8[0] + a8[1]) + (a8[2] + a8[3])) + ((a8[4] + a8[5]) + (a8[6] + a8[7]));
  rs += __shfl_xor(rs, 32);
  l = l * scl + rs;
#pragma unroll
  for (int i = 0; i < 16; ++i) { o0[i] *= scl; o1[i] *= scl; }
  // PV: per kv16-chunk, assemble P B-frag (k-elem kv = hi*8+j within chunk).
  // Lane's regs rb..rb+3 hold chunk-rel {0..3}+4hi, rb+4..rb+7 hold {8..11}+4hi;
  // the missing quad lives in the partner lane (lane^32) -> shfl_xor(32).
#pragma unroll
  for (int c = 0; c < 4; ++c) {
    const int rb = (c & 1) * 8;
    float v0, v1, v2, v3, v4, v5, v6, v7;
    if (c < 2) {
      v0 = s0[rb + 0]; v1 = s0[rb + 1]; v2 = s0[rb + 2]; v3 = s0[rb + 3];
      v4 = s0[rb + 4]; v5 = s0[rb + 5]; v6 = s0[rb + 6]; v7 = s0[rb + 7];
    } else {
      v0 = s1[rb + 0]; v1 = s1[rb + 1]; v2 = s1[rb + 2]; v3 = s1[rb + 3];
      v4 = s1[rb + 4]; v5 = s1[rb + 5]; v6 = s1[rb + 6]; v7 = s1[rb + 7];
    }
    const unsigned int wa = cvtpk(v0, v1), wb = cvtpk(v2, v3);
    const unsigned int wc = cvtpk(v4, v5), wd = cvtpk(v6, v7);
    const unsigned int sa = (unsigned int)__shfl_xor((int)wa, 32);
    const unsigned int sb = (unsigned int)__shfl_xor((int)wb, 32);
    const unsigned int sc_ = (unsigned int)__shfl_xor((int)wc, 32);
    const unsigned int sd = (unsigned int)__shfl_xor((int)wd, 32);
    // hi=0 needs chunk kv 0..7 = {own(0,1),(2,3); partner(4,5),(6,7)}
    // hi=1 needs chunk kv 8..15 = {partner(8,9),(10,11); own(12,13),(14,15)}
    uint4 pw = hi ? make_uint4(sc_, sd, wc, wd) : make_uint4(wa, wb, sa, sb);
    const short8 pf = __builtin_bit_cast(short8, pw);
    o0 = mfma32(vf[0][c], pf, o0);
    o1 = mfma32(vf[1][c], pf, o1);
  }
  if (PREFETCH) load_v32(Vp, kv0 + 64, q31, hi, vf);  // hidden under next QK+softmax
}

__global__ __launch_bounds__(64) void attn_v4(
    const unsigned short* __restrict__ Qb, const unsigned short* __restrict__ Kb,
    const unsigned short* __restrict__ Vt, unsigned short* __restrict__ yb) {
  const int flat = (int)blockIdx.x + ((int)blockIdx.y << 6);  // 0..2047
  const int xcd = flat & 7;              // dispatch round-robins XCDs
  const int rest = flat >> 3;            // 0..255
  const int bh = xcd * 4 + (rest >> 6);  // 4 heads per XCD (2MB K+V < 4MB L2)
  const int qt = 63 - (rest & 63);       // longest q-tile jobs dispatch first
  const int lane = (int)threadIdx.x & 63;
  const int q31 = lane & 31, hi = lane >> 5;
  const int b = bh >> 4, h = bh & 15;
  const int qbase = qt * 32;
  const unsigned short* Kp = Kb + (long)bh * (S_LEN * 64);
  const unsigned short* Vp = Vt + (long)bh * (64 * S_LEN);
  const unsigned short* Qp = Qb + ((long)bh * S_LEN + qbase) * 64;
  short8 qf[4];
#pragma unroll
  for (int dc = 0; dc < 4; ++dc)
    qf[dc] = *(const short8*)(Qp + q31 * 64 + dc * 16 + hi * 8);
  short8 kf[2][4], vf[2][4];
  f32x16 o0 = {}, o1 = {};
  float m = -1e30f, l = 0.f;
  const int nfull = qbase >> 6;

  load_k32(Kp, 0, q31, hi, kf);
  load_v32(Vp, 0, q31, hi, vf);
  for (int t = 0; t < nfull; ++t)
    attn_tile32<false, true>(t * 64, qbase, q31, hi, qf, kf, vf, o0, o1, m, l, Kp, Vp);
  attn_tile32<true, false>(nfull * 64, qbase, q31, hi, qf, kf, vf, o0, o1, m, l, Kp, Vp);

  const float inv = 1.0f / l;
  unsigned short* yrow = yb + ((long)b * S_LEN + qbase + q31) * DMODEL + h * 64;
#pragma unroll
  for (int a2 = 0; a2 < 2; ++a2)
#pragma unroll
    for (int q2 = 0; q2 < 4; ++q2) {
      float e0, e1, e2, e3;
      if (a2 == 0) { e0 = o0[q2 * 4]; e1 = o0[q2 * 4 + 1]; e2 = o0[q2 * 4 + 2]; e3 = o0[q2 * 4 + 3]; }
      else         { e0 = o1[q2 * 4]; e1 = o1[q2 * 4 + 1]; e2 = o1[q2 * 4 + 2]; e3 = o1[q2 * 4 + 3]; }
      uint2 w;
      w.x = cvtpk(e0 * inv, e1 * inv);
      w.y = cvtpk(e2 * inv, e3 * inv);
      // acc elem i=q2*4+j -> dv = j + 8*q2 + 4*hi (+32 for second acc)
      *(uint2*)(yrow + a2 * 32 + q2 * 8 + hi * 4) = w;
    }
}

extern "C" void kernel_launch(void* const* d_in, const int* in_sizes, int n_in,
                              void* d_out, int out_size, void* d_ws, size_t ws_size,
                              hipStream_t stream) {
  const float* x = (const float*)d_in[0];       // [2,2048,1024]
  const float* Wa = (const float*)d_in[1];      // [1024,3072]
  const float* Wp = (const float*)d_in[2];      // [1024,1024]
  float* out = (float*)d_out;

  char* ws = (char*)d_ws;
  size_t off = 0;
  auto alloc = [&](size_t bytes) -> void* {
    off = (off + 255) & ~(size_t)255;
    void* p = ws + off;
    off += bytes;
    return p;
  };
  unsigned short* xb   = (unsigned short*)alloc((size_t)4096 * 1024 * 2);
  unsigned short* WaT  = (unsigned short*)alloc((size_t)3072 * 1024 * 2);
  unsigned short* WpT  = (unsigned short*)alloc((size_t)1024 * 1024 * 2);
  unsigned short* qkvb = (unsigned short*)alloc((size_t)4096 * 3072 * 2);
  float2* tab          = (float2*)alloc((size_t)2048 * 32 * sizeof(float2));
  unsigned short* Qb   = (unsigned short*)alloc((size_t)32 * 2048 * 64 * 2);
  unsigned short* Kb   = (unsigned short*)alloc((size_t)32 * 2048 * 64 * 2);
  unsigned short* Vt   = (unsigned short*)alloc((size_t)32 * 2048 * 64 * 2);
  unsigned short* yb   = xb;  // alias: xb dead after gemm1

  dim3 tB(32, 8);
  cast_f32_bf16<<<4096, 256, 0, stream>>>(x, xb, (long)4096 * 1024);
  transpose_cast<<<dim3(96, 32), tB, 0, stream>>>(Wa, WaT, 1024, 3072);
  transpose_cast<<<dim3(32, 32), tB, 0, stream>>>(Wp, WpT, 1024, 1024);
  make_tab<<<256, 256, 0, stream>>>(tab);
  gemm_bt<1><<<dim3(32, 24), 256, 0, stream>>>(xb, WaT, (void*)qkvb, 4096, 3072, 1024);
  rope_scatter<<<16384, 256, 0, stream>>>(qkvb, tab, Qb, Kb);
  v_transpose<<<dim3(32, 2, 32), tB, 0, stream>>>(qkvb, Vt);
  attn_v4<<<dim3(64, 32), 64, 0, stream>>>(Qb, Kb, Vt, yb);
  gemm_bt<0><<<dim3(32, 8), 256, 0, stream>>>(yb, WpT, (void*)out, 4096, 1024, 1024);
}

// Round 11
// 258.435 us; speedup vs baseline: 1.9562x; 1.0728x over previous
//
#include <hip/hip_runtime.h>
#include <stdint.h>

// Problem constants: B=2, S=2048, D=1024, H=16, HD=64, ROT_DIM=64(=HD)
#define S_LEN 2048
#define NHEAD 16
#define DMODEL 1024

typedef __attribute__((ext_vector_type(8))) short short8;
typedef __attribute__((ext_vector_type(8))) __bf16 bf16x8;
typedef __attribute__((ext_vector_type(4))) float f32x4;
typedef __attribute__((ext_vector_type(16))) float f32x16;

__device__ __forceinline__ unsigned short f2b(float f) {
  unsigned int u = __float_as_uint(f);
  u += 0x7fffu + ((u >> 16) & 1u);   // round-to-nearest-even
  return (unsigned short)(u >> 16);
}
__device__ __forceinline__ float b2f(unsigned short h) {
  return __uint_as_float(((unsigned int)h) << 16);
}
__device__ __forceinline__ f32x4 mfma16(short8 a, short8 b, f32x4 c) {
  return __builtin_amdgcn_mfma_f32_16x16x32_bf16(
      __builtin_bit_cast(bf16x8, a), __builtin_bit_cast(bf16x8, b), c, 0, 0, 0);
}
__device__ __forceinline__ f32x16 mfma32(short8 a, short8 b, f32x16 c) {
  return __builtin_amdgcn_mfma_f32_32x32x16_bf16(
      __builtin_bit_cast(bf16x8, a), __builtin_bit_cast(bf16x8, b), c, 0, 0, 0);
}
__device__ __forceinline__ unsigned int cvtpk(float lo, float hi) {
  unsigned int r;
  asm("v_cvt_pk_bf16_f32 %0, %1, %2" : "=v"(r) : "v"(lo), "v"(hi));
  return r;
}
__device__ __forceinline__ void gload16(const void* g, void* l) {
  __builtin_amdgcn_global_load_lds(
      (const __attribute__((address_space(1))) unsigned int*)g,
      (__attribute__((address_space(3))) unsigned int*)l, 16, 0, 0);
}

// ---------------- cast x (f32 -> bf16), vectorized ----------------
__global__ __launch_bounds__(256) void cast_f32_bf16(
    const float* __restrict__ in, unsigned short* __restrict__ out, long n) {
  long i = ((long)blockIdx.x * 256 + threadIdx.x) * 4;
  if (i >= n) return;
  float4 v = *(const float4*)(in + i);
  ushort4 o;
  o.x = f2b(v.x); o.y = f2b(v.y); o.z = f2b(v.z); o.w = f2b(v.w);
  *(ushort4*)(out + i) = o;
}

// ---------------- transpose + cast: W[K][N] f32 -> Wt[N][K] bf16 ----------------
__global__ __launch_bounds__(256) void transpose_cast(
    const float* __restrict__ W, unsigned short* __restrict__ Wt, int K, int N) {
  __shared__ float t[32][33];
  const int nt = blockIdx.x, kt = blockIdx.y;
  const int tx = threadIdx.x, ty = threadIdx.y; // (32, 8)
#pragma unroll
  for (int j = 0; j < 4; ++j)
    t[ty + j * 8][tx] = W[(long)(kt * 32 + ty + j * 8) * N + nt * 32 + tx];
  __syncthreads();
#pragma unroll
  for (int j = 0; j < 4; ++j)
    Wt[(long)(nt * 32 + ty + j * 8) * K + kt * 32 + tx] = f2b(t[tx][ty + j * 8]);
}

// ---------------- RoPE cos/sin table ----------------
__global__ __launch_bounds__(256) void make_tab(float2* __restrict__ tab) {
  int i = blockIdx.x * 256 + threadIdx.x;  // 2048*32
  if (i >= S_LEN * 32) return;
  int s = i >> 5, fi = i & 31;
  float inv = powf(10000.0f, -(float)(2 * fi) / 64.0f);
  float fr = (float)s * inv;
  tab[i] = make_float2(cosf(fr), sinf(fr));
}

// ---------------- GEMM: C[M][N] = A[M][K](bf16) * Bt[N][K](bf16)^T ----------------
template <int OUT_BF16>
__global__ __launch_bounds__(256) void gemm_bt(
    const unsigned short* __restrict__ A, const unsigned short* __restrict__ Bt,
    void* __restrict__ Cout, int M, int N, int K) {
  __shared__ __align__(16) unsigned short As[128 * 32];
  __shared__ __align__(16) unsigned short Bs[128 * 32];
  const int tid = threadIdx.x;
  const int wave = tid >> 6, lane = tid & 63;
  const int g = lane >> 4, r15 = lane & 15;
  const int wm = wave >> 1, wn = wave & 1;
  const long m0 = (long)blockIdx.x * 128, n0 = (long)blockIdx.y * 128;
  const int srow = tid >> 2, scol = (tid & 3) * 8;  // 16B per thread
  const unsigned short* Ag = A + (m0 + srow) * K + scol;
  const unsigned short* Bg = Bt + (n0 + srow) * K + scol;
  unsigned short* As0 = &As[srow * 32 + scol];
  unsigned short* As1 = &As[(srow + 64) * 32 + scol];
  unsigned short* Bs0 = &Bs[srow * 32 + scol];
  unsigned short* Bs1 = &Bs[(srow + 64) * 32 + scol];
  f32x4 acc[4][4] = {};
  for (int kt = 0; kt < K; kt += 32) {
    __syncthreads();
    gload16(Ag + kt, As0);
    gload16(Ag + (long)64 * K + kt, As1);
    gload16(Bg + kt, Bs0);
    gload16(Bg + (long)64 * K + kt, Bs1);
    __syncthreads();
    short8 a[4], b[4];
#pragma unroll
    for (int m = 0; m < 4; ++m)
      a[m] = *(const short8*)&As[(wm * 64 + m * 16 + r15) * 32 + g * 8];
#pragma unroll
    for (int n = 0; n < 4; ++n)
      b[n] = *(const short8*)&Bs[(wn * 64 + n * 16 + r15) * 32 + g * 8];
#pragma unroll
    for (int m = 0; m < 4; ++m)
#pragma unroll
      for (int n = 0; n < 4; ++n)
        acc[m][n] = mfma16(a[m], b[n], acc[m][n]);
  }
#pragma unroll
  for (int m = 0; m < 4; ++m)
#pragma unroll
    for (int n = 0; n < 4; ++n)
#pragma unroll
      for (int r = 0; r < 4; ++r) {
        long row = m0 + wm * 64 + m * 16 + g * 4 + r;
        long col = n0 + wn * 64 + n * 16 + r15;
        if (OUT_BF16)
          ((unsigned short*)Cout)[row * N + col] = f2b(acc[m][n][r]);
        else
          ((float*)Cout)[row * N + col] = acc[m][n][r];
      }
}

// ---------------- RoPE + scatter q,k ----------------
__global__ __launch_bounds__(256) void rope_scatter(
    const unsigned short* __restrict__ qkv, const float2* __restrict__ tab,
    unsigned short* __restrict__ Qb, unsigned short* __restrict__ Kb) {
  long p = (long)blockIdx.x * 256 + threadIdx.x;  // pair index, 4096*1024 total
  if (p >= (long)4096 * 1024) return;
  int row = (int)(p >> 10);
  int col = ((int)(p & 1023)) * 2;
  int seg = col >> 10;            // 0=q, 1=k
  int cc = col & 1023;
  int h = cc >> 6, d = cc & 63;
  int b = row >> 11, s = row & 2047;
  const unsigned short* src = qkv + (long)row * 3072 + col;
  float v0 = b2f(src[0]), v1 = b2f(src[1]);
  float2 f = tab[s * 32 + (d >> 1)];
  float o0 = v0 * f.x + v1 * f.y;
  float o1 = v1 * f.x - v0 * f.y;
  float scl = seg ? 1.0f : 0.125f;  // q pre-scaled by 1/sqrt(HD)
  unsigned short* dst = (seg ? Kb : Qb) + (((long)(b * NHEAD + h) * S_LEN + s) * 64 + d);
  dst[0] = f2b(o0 * scl);
  dst[1] = f2b(o1 * scl);
}

// ---------------- V transpose (plain): Vt[bh][d][kv] ----------------
__global__ __launch_bounds__(256) void v_transpose(
    const unsigned short* __restrict__ qkv, unsigned short* __restrict__ Vt) {
  __shared__ unsigned short t[64][33];
  const int st = blockIdx.x;   // 32 tiles of 64 kv
  const int dt = blockIdx.y;   // 2 tiles of 32 d
  const int bh = blockIdx.z;   // 32
  const int b = bh >> 4, h = bh & 15;
  const int tx = threadIdx.x, ty = threadIdx.y;  // (32, 8)
#pragma unroll
  for (int j = 0; j < 8; ++j)
    t[ty + j * 8][tx] =
        qkv[((long)b * S_LEN + st * 64 + ty + j * 8) * 3072 + 2048 + h * 64 + dt * 32 + tx];
  __syncthreads();
#pragma unroll
  for (int j = 0; j < 4; ++j) {
    const int d_local = ty + j * 8;          // 0..31
#pragma unroll
    for (int jj = 0; jj < 2; ++jj) {
      const int col = jj * 32 + tx;          // 0..63
      Vt[((long)bh * 64 + dt * 32 + d_local) * S_LEN + st * 64 + col] = t[col][d_local];
    }
  }
}

// ---------------- flash attention v5: v4 core + intra-block KV-split ----------------
// 4 waves per block, same (bh, 32q) tile; wave w does kv-tiles t = w, w+4, ...
// with private online-softmax state. LDS combine at the end (exact math:
// m* = max m_w; O* = sum c_w O_w, l* = sum c_w l_w, c_w = exp(m_w - m*)).
// 8192 waves supplied (was 2048) and 4x shorter per-wave serial chains -> the
// round-10 occupancy/latency bottleneck (11% occ, <1 wave/SIMD avg) lifts.
__device__ __forceinline__ void load_k32(const unsigned short* __restrict__ Kp,
                                         int kv0, int q31, int hi, short8 kf[2][4]) {
#pragma unroll
  for (int sub = 0; sub < 2; ++sub)
#pragma unroll
    for (int dc = 0; dc < 4; ++dc)
      kf[sub][dc] = *(const short8*)(Kp + (long)(kv0 + sub * 32 + q31) * 64 + dc * 16 + hi * 8);
}
__device__ __forceinline__ void load_v32(const unsigned short* __restrict__ Vp,
                                         int kv0, int q31, int hi, short8 vf[2][4]) {
#pragma unroll
  for (int dv = 0; dv < 2; ++dv)
#pragma unroll
    for (int c = 0; c < 4; ++c)
      vf[dv][c] = *(const short8*)(Vp + (long)(dv * 32 + q31) * S_LEN + kv0 + c * 16 + hi * 8);
}

__device__ __forceinline__ void attn_tile32(
    int kv0, int qbase, int q31, int hi, bool masked, bool pre, int kvn,
    const short8 qf[4], short8 kf[2][4], short8 vf[2][4],
    f32x16& o0, f32x16& o1, float& m, float& l,
    const unsigned short* __restrict__ Kp, const unsigned short* __restrict__ Vp) {
  f32x16 s0 = {}, s1 = {};
#pragma unroll
  for (int dc = 0; dc < 4; ++dc) s0 = mfma32(kf[0][dc], qf[dc], s0);
#pragma unroll
  for (int dc = 0; dc < 4; ++dc) s1 = mfma32(kf[1][dc], qf[dc], s1);
  if (pre) load_k32(Kp, kvn, q31, hi, kf);  // hidden under softmax+PV
  if (masked) {
    const int q = qbase + q31;
#pragma unroll
    for (int i = 0; i < 16; ++i) {
      const int rel = (i & 3) + 8 * (i >> 2) + 4 * hi;
      s0[i] = (kv0 + rel <= q) ? s0[i] : -1e30f;
      s1[i] = (kv0 + 32 + rel <= q) ? s1[i] : -1e30f;
    }
  }
  // row max over 64 kv: in-register tree over 32 + one cross-half shfl
  float t8[8];
#pragma unroll
  for (int i = 0; i < 8; ++i)
    t8[i] = fmaxf(fmaxf(s0[2 * i], s0[2 * i + 1]), fmaxf(s1[2 * i], s1[2 * i + 1]));
  float mt = fmaxf(fmaxf(fmaxf(t8[0], t8[1]), fmaxf(t8[2], t8[3])),
                   fmaxf(fmaxf(t8[4], t8[5]), fmaxf(t8[6], t8[7])));
  mt = fmaxf(mt, __shfl_xor(mt, 32));
  const float mnew = fmaxf(m, mt);
  const float scl = __expf(m - mnew);
  m = mnew;
#pragma unroll
  for (int i = 0; i < 16; ++i) {
    s0[i] = __expf(s0[i] - mnew);
    s1[i] = __expf(s1[i] - mnew);
  }
  float a8[8];
#pragma unroll
  for (int i = 0; i < 8; ++i)
    a8[i] = (s0[2 * i] + s0[2 * i + 1]) + (s1[2 * i] + s1[2 * i + 1]);
  float rs = ((a8[0] + a8[1]) + (a8[2] + a8[3])) + ((a8[4] + a8[5]) + (a8[6] + a8[7]));
  rs += __shfl_xor(rs, 32);
  l = l * scl + rs;
#pragma unroll
  for (int i = 0; i < 16; ++i) { o0[i] *= scl; o1[i] *= scl; }
  // PV: per kv16-chunk, assemble P B-frag; partner quad via shfl_xor(32).
#pragma unroll
  for (int c = 0; c < 4; ++c) {
    const int rb = (c & 1) * 8;
    float v0, v1, v2, v3, v4, v5, v6, v7;
    if (c < 2) {
      v0 = s0[rb + 0]; v1 = s0[rb + 1]; v2 = s0[rb + 2]; v3 = s0[rb + 3];
      v4 = s0[rb + 4]; v5 = s0[rb + 5]; v6 = s0[rb + 6]; v7 = s0[rb + 7];
    } else {
      v0 = s1[rb + 0]; v1 = s1[rb + 1]; v2 = s1[rb + 2]; v3 = s1[rb + 3];
      v4 = s1[rb + 4]; v5 = s1[rb + 5]; v6 = s1[rb + 6]; v7 = s1[rb + 7];
    }
    const unsigned int wa = cvtpk(v0, v1), wb = cvtpk(v2, v3);
    const unsigned int wc = cvtpk(v4, v5), wd = cvtpk(v6, v7);
    const unsigned int sa = (unsigned int)__shfl_xor((int)wa, 32);
    const unsigned int sb = (unsigned int)__shfl_xor((int)wb, 32);
    const unsigned int sc_ = (unsigned int)__shfl_xor((int)wc, 32);
    const unsigned int sd = (unsigned int)__shfl_xor((int)wd, 32);
    uint4 pw = hi ? make_uint4(sc_, sd, wc, wd) : make_uint4(wa, wb, sa, sb);
    const short8 pf = __builtin_bit_cast(short8, pw);
    o0 = mfma32(vf[0][c], pf, o0);
    o1 = mfma32(vf[1][c], pf, o1);
  }
  if (pre) load_v32(Vp, kvn, q31, hi, vf);  // hidden under next QK+softmax
}

__global__ __launch_bounds__(256) void attn_v5(
    const unsigned short* __restrict__ Qb, const unsigned short* __restrict__ Kb,
    const unsigned short* __restrict__ Vt, unsigned short* __restrict__ yb) {
  __shared__ float Om[4][64][33];   // [wave][lane][0..31], pad 33 -> conflict-free
  __shared__ float Ml[4][64][2];    // (m, l) per wave per lane
  const int flat = (int)blockIdx.x + ((int)blockIdx.y << 6);  // 0..2047
  const int xcd = flat & 7;              // dispatch round-robins XCDs
  const int rest = flat >> 3;            // 0..255
  const int bh = xcd * 4 + (rest >> 6);  // 4 heads per XCD (2MB K+V < 4MB L2)
  const int qt = 63 - (rest & 63);       // longest q-tile jobs dispatch first
  const int tid = (int)threadIdx.x;
  const int w = tid >> 6, lane = tid & 63;
  const int q31 = lane & 31, hi = lane >> 5;
  const int b = bh >> 4, h = bh & 15;
  const int qbase = qt * 32;
  const unsigned short* Kp = Kb + (long)bh * (S_LEN * 64);
  const unsigned short* Vp = Vt + (long)bh * (64 * S_LEN);
  const unsigned short* Qp = Qb + ((long)bh * S_LEN + qbase) * 64;
  short8 qf[4];
#pragma unroll
  for (int dc = 0; dc < 4; ++dc)
    qf[dc] = *(const short8*)(Qp + q31 * 64 + dc * 16 + hi * 8);
  short8 kf[2][4], vf[2][4];
  f32x16 o0 = {}, o1 = {};
  float m = -1e30f, l = 0.f;
  const int nfull = qbase >> 6;  // tiles 0..nfull; tile nfull is masked

  if (w <= nfull) {
    load_k32(Kp, w * 64, q31, hi, kf);
    load_v32(Vp, w * 64, q31, hi, vf);
    for (int t = w; t <= nfull; t += 4) {
      const bool masked = (t == nfull);
      const bool more = (t + 4 <= nfull);
      attn_tile32(t * 64, qbase, q31, hi, masked, more, (t + 4) * 64,
                  qf, kf, vf, o0, o1, m, l, Kp, Vp);
    }
  }

  // publish partial state
  Ml[w][lane][0] = m;
  Ml[w][lane][1] = l;
#pragma unroll
  for (int i = 0; i < 16; ++i) {
    Om[w][lane][i] = o0[i];
    Om[w][lane][16 + i] = o1[i];
  }
  __syncthreads();

  // exact combine (all waves compute coefficients; each writes 2 of 8 chunks)
  const float m0 = Ml[0][lane][0], m1 = Ml[1][lane][0];
  const float m2 = Ml[2][lane][0], m3 = Ml[3][lane][0];
  const float ms = fmaxf(fmaxf(m0, m1), fmaxf(m2, m3));
  const float c0 = __expf(m0 - ms), c1 = __expf(m1 - ms);
  const float c2 = __expf(m2 - ms), c3 = __expf(m3 - ms);
  const float ls = c0 * Ml[0][lane][1] + c1 * Ml[1][lane][1] +
                   c2 * Ml[2][lane][1] + c3 * Ml[3][lane][1];
  const float inv = 1.0f / ls;
  unsigned short* yrow = yb + ((long)b * S_LEN + qbase + q31) * DMODEL + h * 64;
#pragma unroll
  for (int k = 0; k < 2; ++k) {
    const int p8 = w * 2 + k;
    const int a2 = p8 >> 2, q2 = p8 & 3;
    const int base = a2 * 16 + q2 * 4;
    float e[4];
#pragma unroll
    for (int j = 0; j < 4; ++j)
      e[j] = (c0 * Om[0][lane][base + j] + c1 * Om[1][lane][base + j] +
              c2 * Om[2][lane][base + j] + c3 * Om[3][lane][base + j]) * inv;
    uint2 wv;
    wv.x = cvtpk(e[0], e[1]);
    wv.y = cvtpk(e[2], e[3]);
    *(uint2*)(yrow + a2 * 32 + q2 * 8 + hi * 4) = wv;
  }
}

extern "C" void kernel_launch(void* const* d_in, const int* in_sizes, int n_in,
                              void* d_out, int out_size, void* d_ws, size_t ws_size,
                              hipStream_t stream) {
  const float* x = (const float*)d_in[0];       // [2,2048,1024]
  const float* Wa = (const float*)d_in[1];      // [1024,3072]
  const float* Wp = (const float*)d_in[2];      // [1024,1024]
  float* out = (float*)d_out;

  char* ws = (char*)d_ws;
  size_t off = 0;
  auto alloc = [&](size_t bytes) -> void* {
    off = (off + 255) & ~(size_t)255;
    void* p = ws + off;
    off += bytes;
    return p;
  };
  unsigned short* xb   = (unsigned short*)alloc((size_t)4096 * 1024 * 2);
  unsigned short* WaT  = (unsigned short*)alloc((size_t)3072 * 1024 * 2);
  unsigned short* WpT  = (unsigned short*)alloc((size_t)1024 * 1024 * 2);
  unsigned short* qkvb = (unsigned short*)alloc((size_t)4096 * 3072 * 2);
  float2* tab          = (float2*)alloc((size_t)2048 * 32 * sizeof(float2));
  unsigned short* Qb   = (unsigned short*)alloc((size_t)32 * 2048 * 64 * 2);
  unsigned short* Kb   = (unsigned short*)alloc((size_t)32 * 2048 * 64 * 2);
  unsigned short* Vt   = (unsigned short*)alloc((size_t)32 * 2048 * 64 * 2);
  unsigned short* yb   = xb;  // alias: xb dead after gemm1

  dim3 tB(32, 8);
  cast_f32_bf16<<<4096, 256, 0, stream>>>(x, xb, (long)4096 * 1024);
  transpose_cast<<<dim3(96, 32), tB, 0, stream>>>(Wa, WaT, 1024, 3072);
  transpose_cast<<<dim3(32, 32), tB, 0, stream>>>(Wp, WpT, 1024, 1024);
  make_tab<<<256, 256, 0, stream>>>(tab);
  gemm_bt<1><<<dim3(32, 24), 256, 0, stream>>>(xb, WaT, (void*)qkvb, 4096, 3072, 1024);
  rope_scatter<<<16384, 256, 0, stream>>>(qkvb, tab, Qb, Kb);
  v_transpose<<<dim3(32, 2, 32), tB, 0, stream>>>(qkvb, Vt);
  attn_v5<<<dim3(64, 32), 256, 0, stream>>>(Qb, Kb, Vt, yb);
  gemm_bt<0><<<dim3(32, 8), 256, 0, stream>>>(yb, WpT, (void*)out, 4096, 1024, 1024);
}